// Round 4
// baseline (210.137 us; speedup 1.0000x reference)
//
#include <hip/hip_runtime.h>
#include <hip/hip_bf16.h>
#include <hip/hip_cooperative_groups.h>

// SimilarityPreserving loss, O(b*d^2) factorization (b=8192, d=128):
//   loss = (1/b^2) * sum_i 2*(1 - rho_i),  rho_i = C_i / sqrt(A_i*B_i)
//   A_i = xt_i^T Gt xt_i,  Gt = Yt_hat^T Yt_hat  (Yt_hat = row-normalized zyt)
//   B_i = xs_i^T Gs xs_i,  Gs = Ys_hat^T Ys_hat
//   C_i = xt_i^T M  xs_i,  M  = Yt_hat^T Ys_hat
// X normalization and temperature fold out of rho (scale invariance); eps
// never binds. Math verified R5/R6 (absmax 0.0).
//
// R11 (post-mortem of R10: NP 64->32 halved gram's grid to 96 blocks = 37%
// of CUs; lost parallelism ate the store savings -> revert to NP=64.
// Remaining controllable slack = 3 launch gaps between 4 dependent
// dispatches):
//  - ONE cooperative kernel, 256 blocks x 512 thr (8 waves/CU, 1 block/CU,
//    co-resident by construction), grid.sync() between phases. This is the
//    sanctioned replacement for R9's fatal hand-rolled spin barrier: launch
//    validates co-residency and FAILS (error code) rather than hanging.
//  - Host checks the return code; on failure falls back to 4 standalone
//    kernels with the IDENTICAL __device__ phase bodies (= R8 structure).
//  - Phase geometry: prep 256x4 slots = 1024 units exactly; gram = R8's
//    verified 192-block NP=64 shape (blocks 192..255 idle); reduce 96
//    blocks x 512 = 49152 = 3*16384 exactly; quad 256 blocks x 32 rows,
//    8 waves (wave = rowgrp g x nt-quarter hq).

namespace cg = cooperative_groups;

typedef __attribute__((ext_vector_type(8))) short short8;   // 8 bf16
typedef __attribute__((ext_vector_type(4))) float float4v;  // MFMA C/D

#define BSZ 8192
#define DIM 128
#define NP  64           // k-splits per gram (K=128 each)
#define INV_B2 1.4901161193847656e-08f  // 1/8192^2

__device__ __forceinline__ short f2bf(float x) {
    union { __hip_bfloat16 b; short s; } u;
    u.b = __float2bfloat16(x);
    return u.s;
}

// ---------------------------------------------------------------- phase 0
// prep: 256 blocks x 4 slots(128 thr) = 1024 units = (mat 0..1) x (16-row
// group 0..511). Thread owns column d for 16 rows; coalesced row loads,
// per-thread contiguous 32 B transposed bf16 store into YT[mat][d][8192].
__device__ __forceinline__ void do_prep(
    int bid, int tid,
    const float* __restrict__ Yt, const float* __restrict__ Ys,
    short* __restrict__ YT, float* __restrict__ out)
{
    __shared__ float rsum[8][16];
    __shared__ float invn[4][16];

    const int lane = tid & 63, wave = tid >> 6;
    const int slot = tid >> 7, d = tid & 127;
    const int u = bid * 4 + slot;          // 0..1023
    const int mat = u >> 9, rg = u & 511;  // 16-row group
    const float* Y = mat ? Ys : Yt;

    if (bid == 0 && tid == 0) out[0] = 0.f;

    float v[16];
    const float* base = Y + (size_t)(rg * 16) * DIM + d;
    #pragma unroll
    for (int i = 0; i < 16; ++i) v[i] = base[(size_t)i * DIM];

    #pragma unroll
    for (int i = 0; i < 16; ++i) {
        float ss = v[i] * v[i];
        #pragma unroll
        for (int off = 1; off < 64; off <<= 1) ss += __shfl_xor(ss, off);
        if (lane == 0) rsum[wave][i] = ss;
    }
    __syncthreads();
    if (tid < 64) {
        int s = tid >> 4, i = tid & 15;
        float sum = rsum[2 * s][i] + rsum[2 * s + 1][i];
        invn[s][i] = (sum > 0.f) ? rsqrtf(sum) : 0.f;
    }
    __syncthreads();

    short* yt = YT + ((size_t)mat * 128 + d) * BSZ + rg * 16;
    #pragma unroll
    for (int g = 0; g < 2; ++g) {
        short8 pk;
        #pragma unroll
        for (int j = 0; j < 8; ++j) {
            int i = g * 8 + j;
            pk[j] = f2bf(v[i] * invn[slot][i]);
        }
        *(short8*)&yt[g * 8] = pk;
    }
}

// ---------------------------------------------------------------- phase 1
// gram: blocks 0..191 = (gram 0..2, split 0..63). fp32 partial G over
// k-rows [split*128,+128). 8 waves, wave = d1-strip; fragments are direct
// contiguous 16B loads from YT. 32 MFMA/wave, no LDS. (R8-verified shape.)
__device__ __forceinline__ void do_gram(
    int bid, int tid,
    const short* __restrict__ YT, float* __restrict__ partial)
{
    const int lane = tid & 63;
    const int s1   = tid >> 6;    // wave = d1 strip 0..7
    const int q    = lane >> 4;
    const int l15  = lane & 15;
    const int gram  = bid >> 6;   // 0=Gt 1=Gs 2=M
    const int split = bid & 63;   // 0..NP-1

    const short* Ta = (gram == 1) ? YT + (size_t)128 * BSZ : YT;  // Gs->Ys
    const short* Tb = (gram == 0) ? YT : YT + (size_t)128 * BSZ;  // Gt->Yt
    const int k0 = split * 128;

    float4v acc[8];
    #pragma unroll
    for (int s2 = 0; s2 < 8; ++s2) acc[s2] = (float4v){0.f, 0.f, 0.f, 0.f};

    #pragma unroll
    for (int kk = 0; kk < 4; ++kk) {
        const int ko = k0 + kk * 32 + q * 8;
        short8 fa = *(const short8*)&Ta[(size_t)(s1 * 16 + l15) * BSZ + ko];
        short8 fb[8];
        #pragma unroll
        for (int s2 = 0; s2 < 8; ++s2)
            fb[s2] = *(const short8*)&Tb[(size_t)(s2 * 16 + l15) * BSZ + ko];
        #pragma unroll
        for (int s2 = 0; s2 < 8; ++s2)
            acc[s2] = __builtin_amdgcn_mfma_f32_16x16x32_bf16(fa, fb[s2], acc[s2], 0, 0, 0);
    }

    // D tile: d1 = s1*16 + q*4 + r, d2 = s2*16 + l15.
    float* P = partial + ((size_t)(gram * NP + split) << 14);
    #pragma unroll
    for (int s2 = 0; s2 < 8; ++s2)
        #pragma unroll
        for (int r = 0; r < 4; ++r)
            P[((s1 * 16 + q * 4 + r) << 7) + s2 * 16 + l15] = acc[s2][r];
}

// ---------------------------------------------------------------- phase 2
// reduce: blocks 0..95, one G element per thread (96*512 == 3*16384).
// Store transposed Gb[g][d2][d1] bf16 so quad's B-frags are contiguous.
__device__ __forceinline__ void do_reduce(
    int bid, int tid,
    const float* __restrict__ partial, __hip_bfloat16* __restrict__ Gb)
{
    const int o = bid * 512 + tid;        // < 3*16384
    const int g = o >> 14, rem = o & 16383;
    float s = 0.f;
    #pragma unroll
    for (int b = 0; b < NP; ++b)
        s += partial[((size_t)(g * NP + b) << 14) + rem];
    Gb[(g << 14) + ((rem & 127) << 7) + (rem >> 7)] = __float2bfloat16(s);
}

// ---------------------------------------------------------------- phase 3
// quad: 256 blocks x 32 rows. 8 waves: wave = (rowgrp g = wave&1 -> 16
// rows, nt-quarter hq = wave>>1 -> 2 of 8 d2-strips). Per-row A/B/C
// combined across the 4 hq-waves in LDS; wave 0 computes rho + block
// reduce + atomicAdd.
__device__ __forceinline__ void do_quad(
    int bid, int tid,
    const float* __restrict__ Xt, const float* __restrict__ Xs,
    const __hip_bfloat16* __restrict__ Gb, float* __restrict__ out)
{
    __shared__ float cmb[2][16][4][3];

    const int lane = tid & 63;
    const int wave = tid >> 6;
    const int q    = lane >> 4;
    const int l15  = lane & 15;
    const int g    = wave & 1;      // row group within block
    const int hq   = wave >> 1;     // nt quarter 0..3
    const int rbase = bid * 32 + g * 16;

    // A-frags: lane holds X[rbase+l15][kk*32+q*8 ..+8) as bf16
    short8 At[4], As[4];
    #pragma unroll
    for (int kk = 0; kk < 4; ++kk) {
        const float* pt = Xt + (size_t)(rbase + l15) * DIM + kk * 32 + q * 8;
        const float* ps = Xs + (size_t)(rbase + l15) * DIM + kk * 32 + q * 8;
        float4 t0 = *(const float4*)pt, t1 = *(const float4*)(pt + 4);
        float4 s0 = *(const float4*)ps, s1 = *(const float4*)(ps + 4);
        short8 a, b;
        a[0]=f2bf(t0.x); a[1]=f2bf(t0.y); a[2]=f2bf(t0.z); a[3]=f2bf(t0.w);
        a[4]=f2bf(t1.x); a[5]=f2bf(t1.y); a[6]=f2bf(t1.z); a[7]=f2bf(t1.w);
        b[0]=f2bf(s0.x); b[1]=f2bf(s0.y); b[2]=f2bf(s0.z); b[3]=f2bf(s0.w);
        b[4]=f2bf(s1.x); b[5]=f2bf(s1.y); b[6]=f2bf(s1.z); b[7]=f2bf(s1.w);
        At[kk] = a; As[kk] = b;
    }

    float fA[4] = {0,0,0,0}, fB[4] = {0,0,0,0}, fC[4] = {0,0,0,0};
    const short* G = (const short*)Gb;

    #pragma unroll
    for (int nti = 0; nti < 2; ++nti) {
        int d2 = (hq * 2 + nti) * 16 + l15;
        float4v qt = {0.f,0.f,0.f,0.f}, qs = qt, qc = qt;
        #pragma unroll
        for (int kk = 0; kk < 4; ++kk) {
            int off = (d2 << 7) + kk * 32 + q * 8;
            short8 Bt = *(const short8*)&G[off];
            short8 Bs = *(const short8*)&G[16384 + off];
            short8 Bm = *(const short8*)&G[32768 + off];
            qt = __builtin_amdgcn_mfma_f32_16x16x32_bf16(At[kk], Bt, qt, 0, 0, 0);
            qs = __builtin_amdgcn_mfma_f32_16x16x32_bf16(As[kk], Bs, qs, 0, 0, 0);
            qc = __builtin_amdgcn_mfma_f32_16x16x32_bf16(At[kk], Bm, qc, 0, 0, 0);
        }
        // fold: D row = q*4+r, col = l15 -> Q[row][d2]; A += Q*x, etc.
        #pragma unroll
        for (int r = 0; r < 4; ++r) {
            int row = rbase + q * 4 + r;
            float xtv = Xt[(size_t)row * DIM + d2];
            float xsv = Xs[(size_t)row * DIM + d2];
            fA[r] += qt[r] * xtv;
            fB[r] += qs[r] * xsv;
            fC[r] += qc[r] * xsv;
        }
    }

    #pragma unroll
    for (int r = 0; r < 4; ++r) {
        float A = fA[r], B = fB[r], C = fC[r];
        #pragma unroll
        for (int off = 1; off < 16; off <<= 1) {
            A += __shfl_xor(A, off);
            B += __shfl_xor(B, off);
            C += __shfl_xor(C, off);
        }
        if (l15 == 0) {
            cmb[g][q * 4 + r][hq][0] = A;
            cmb[g][q * 4 + r][hq][1] = B;
            cmb[g][q * 4 + r][hq][2] = C;
        }
    }
    __syncthreads();

    if (wave == 0) {
        float wl = 0.f;
        if (tid < 32) {
            int gg = tid >> 4, row = tid & 15;
            float A = cmb[gg][row][0][0] + cmb[gg][row][1][0]
                    + cmb[gg][row][2][0] + cmb[gg][row][3][0];
            float B = cmb[gg][row][0][1] + cmb[gg][row][1][1]
                    + cmb[gg][row][2][1] + cmb[gg][row][3][1];
            float C = cmb[gg][row][0][2] + cmb[gg][row][1][2]
                    + cmb[gg][row][2][2] + cmb[gg][row][3][2];
            wl = 2.f - 2.f * C * rsqrtf(A * B);
        }
        #pragma unroll
        for (int off = 1; off < 64; off <<= 1) wl += __shfl_xor(wl, off);
        if (tid == 0) atomicAdd(out, wl * INV_B2);
    }
}

// ---------------------------------------------------------------- fused
__global__ __launch_bounds__(512) void fused(
    const float* __restrict__ Xt, const float* __restrict__ Xs,
    const float* __restrict__ Yt, const float* __restrict__ Ys,
    short* __restrict__ YT, float* __restrict__ partial,
    __hip_bfloat16* __restrict__ Gb, float* __restrict__ out)
{
    cg::grid_group grid = cg::this_grid();
    const int bid = blockIdx.x, tid = threadIdx.x;

    do_prep(bid, tid, Yt, Ys, YT, out);
    grid.sync();
    if (bid < 192) do_gram(bid, tid, YT, partial);
    grid.sync();
    if (bid < 96) do_reduce(bid, tid, partial, Gb);
    grid.sync();
    do_quad(bid, tid, Xt, Xs, Gb, out);
}

// ------------------------------------------------- standalone fallbacks
__global__ __launch_bounds__(512) void prep_k(
    const float* __restrict__ Yt, const float* __restrict__ Ys,
    short* __restrict__ YT, float* __restrict__ out)
{ do_prep(blockIdx.x, threadIdx.x, Yt, Ys, YT, out); }

__global__ __launch_bounds__(512) void gram_k(
    const short* __restrict__ YT, float* __restrict__ partial)
{ do_gram(blockIdx.x, threadIdx.x, YT, partial); }

__global__ __launch_bounds__(512) void reduce_k(
    const float* __restrict__ partial, __hip_bfloat16* __restrict__ Gb)
{ do_reduce(blockIdx.x, threadIdx.x, partial, Gb); }

__global__ __launch_bounds__(512) void quad_kk(
    const float* __restrict__ Xt, const float* __restrict__ Xs,
    const __hip_bfloat16* __restrict__ Gb, float* __restrict__ out)
{ do_quad(blockIdx.x, threadIdx.x, Xt, Xs, Gb, out); }

// ---------------------------------------------------------------- launch
extern "C" void kernel_launch(void* const* d_in, const int* in_sizes, int n_in,
                              void* d_out, int out_size, void* d_ws, size_t ws_size,
                              hipStream_t stream) {
    const float* Xs = (const float*)d_in[0];   // zxs
    const float* Ys = (const float*)d_in[1];   // zys
    const float* Xt = (const float*)d_in[2];   // zxt
    const float* Yt = (const float*)d_in[3];   // zyt
    // d_in[4] = temperature: folds out of rho, unused.
    float* out = (float*)d_out;

    char* ws = (char*)d_ws;
    short* YT = (short*)ws;                                    // 2 x 128 x 8192 bf16 = 4 MB
    float* partial = (float*)(ws + (size_t)4 * 1024 * 1024);   // 3*NP*16384 fp32 = 12.6 MB
    __hip_bfloat16* Gb = (__hip_bfloat16*)(ws + (size_t)4 * 1024 * 1024
                                              + (size_t)3 * NP * 16384 * sizeof(float));

    void* args[8] = { (void*)&Xt, (void*)&Xs, (void*)&Yt, (void*)&Ys,
                      (void*)&YT, (void*)&partial, (void*)&Gb, (void*)&out };
    hipError_t e = hipLaunchCooperativeKernel((const void*)fused, dim3(256),
                                              dim3(512), args, 0, stream);
    if (e != hipSuccess) {
        (void)hipGetLastError();   // clear sticky error, take the 4-kernel path
        prep_k  <<<256, 512, 0, stream>>>(Yt, Ys, YT, out);
        gram_k  <<<192, 512, 0, stream>>>(YT, partial);
        reduce_k<<< 96, 512, 0, stream>>>(partial, Gb);
        quad_kk <<<256, 512, 0, stream>>>(Xt, Xs, Gb, out);
    }
}

// Round 6
// 101.463 us; speedup vs baseline: 2.0711x; 2.0711x over previous
//
#include <hip/hip_runtime.h>
#include <hip/hip_bf16.h>

// SimilarityPreserving loss, O(b*d^2) factorization (b=8192, d=128):
//   loss = (1/b^2) * sum_i 2*(1 - rho_i),  rho_i = C_i / sqrt(A_i*B_i)
//   A_i = xt_i^T Gt xt_i,  Gt = Yt_hat^T Yt_hat  (Yt_hat = row-normalized zyt)
//   B_i = xs_i^T Gs xs_i,  Gs = Ys_hat^T Ys_hat
//   C_i = xt_i^T M  xs_i,  M  = Yt_hat^T Ys_hat
// X normalization and temperature fold out of rho (scale invariance); eps
// never binds. Math verified R5/R6 (absmax 0.0).
//
// R13 (post-mortem of R12: tripwire NaN on 1-of-5 single launches while
// correctness + timed graph passed. Full line-by-line re-derivation of
// gram_direct found no race: k-slice coverage, LDS write/read sets, D
// row/col mapping, Gb layout all verified. Deterministic bug would fail
// every launch; session has documented infra flakes (2 container deaths).
// => ONE minimal-diff repro. If it tripwires again: real race, permanent
// revert to R8 4-kernel structure. Only change vs R12: 4 accumulators in
// gram_direct (ILP), semantics identical.):
//  - gram_direct: 192 blocks = 3 grams x 64 (16x16) tiles; full K=8192 per
//    block (8 waves x 1024-k slice x 32 MFMA, 4 accumulators), 8KB LDS
//    cross-wave reduce, direct bf16 store to Gb[g][d2][d1]. YT (4MB) is
//    L2/L3-resident. No partial slab, no reduce dispatch.
//  - prep / quad_k byte-identical to the R10-verified versions.

typedef __attribute__((ext_vector_type(8))) short short8;   // 8 bf16
typedef __attribute__((ext_vector_type(4))) float float4v;  // MFMA C/D

#define BSZ 8192
#define DIM 128
#define INV_B2 1.4901161193847656e-08f  // 1/8192^2

__device__ __forceinline__ short f2bf(float x) {
    union { __hip_bfloat16 b; short s; } u;
    u.b = __float2bfloat16(x);
    return u.s;
}

// ---------------------------------------------------------------- stage 0
// prep: block (chunk, mat) normalizes 32 rows of one Y and writes them
// TRANSPOSED bf16 into YT[mat][d][8192]. Thread owns column d for 16 rows:
// loads are coalesced (256B/row-instr), transposed stores are per-thread
// contiguous 32 B (= one HBM sector, no RMW). Norms: 64-lane shfl + LDS.
__global__ __launch_bounds__(256) void prep(
    const float* __restrict__ Yt, const float* __restrict__ Ys,
    short* __restrict__ YT, float* __restrict__ out)
{
    __shared__ float rsum[2][32];
    __shared__ float invn[32];

    const int tid   = threadIdx.x;
    const int lane  = tid & 63;
    const int wave  = tid >> 6;     // 0..3; wave&1 = d-half
    const int d     = tid & 127;
    const int khalf = tid >> 7;     // 0/1: row half (rows 0-15 / 16-31)
    const int chunk = blockIdx.x;   // 0..255 (32 rows each)
    const int mat   = blockIdx.y;   // 0..1
    const float* Y  = mat ? Ys : Yt;

    if (chunk == 0 && mat == 0 && tid == 0) out[0] = 0.f;

    float v[16];
    const float* base = Y + (size_t)(chunk * 32 + khalf * 16) * DIM + d;
    #pragma unroll
    for (int i = 0; i < 16; ++i) v[i] = base[(size_t)i * DIM];

    #pragma unroll
    for (int i = 0; i < 16; ++i) {
        float ss = v[i] * v[i];
        #pragma unroll
        for (int off = 1; off < 64; off <<= 1) ss += __shfl_xor(ss, off);
        if (lane == 0) rsum[wave & 1][khalf * 16 + i] = ss;
    }
    __syncthreads();
    if (tid < 32) {
        float s = rsum[0][tid] + rsum[1][tid];
        invn[tid] = (s > 0.f) ? rsqrtf(s) : 0.f;
    }
    __syncthreads();

    short* yt = YT + ((size_t)mat * 128 + d) * BSZ + chunk * 32 + khalf * 16;
    #pragma unroll
    for (int g = 0; g < 2; ++g) {
        short8 pk;
        #pragma unroll
        for (int j = 0; j < 8; ++j) {
            int i = g * 8 + j;
            pk[j] = f2bf(v[i] * invn[khalf * 16 + i]);
        }
        *(short8*)&yt[g * 8] = pk;
    }
}

// ---------------------------------------------------------------- stage 1
// gram_direct: block (tile, gram); 3 grams x 64 tiles of 16x16. Full
// K=8192 per block: wave w covers k in [w*1024, +1024), 32 MFMA chained
// through 4 independent accumulators. Cross-wave reduce via LDS, direct
// bf16 store to Gb[g][d2][d1] (contiguous: consecutive tid -> consecutive
// d1). All fragment loads hit L2/L3 (YT = 4MB, resident after prep).
__global__ __launch_bounds__(512) void gram_direct(
    const short* __restrict__ YT, __hip_bfloat16* __restrict__ Gb)
{
    __shared__ float red[8][256];

    const int tid  = threadIdx.x;
    const int lane = tid & 63;
    const int w    = tid >> 6;    // wave = k-slice 0..7
    const int q    = lane >> 4;
    const int l15  = lane & 15;
    const int gram = blockIdx.x >> 6;         // 0=Gt 1=Gs 2=M
    const int t    = blockIdx.x & 63;
    const int ti   = t >> 3, tj = t & 7;      // 16-row d1/d2 panels

    const short* Ta = (gram == 1) ? YT + (size_t)128 * BSZ : YT;  // Gs->Ys
    const short* Tb = (gram == 0) ? YT : YT + (size_t)128 * BSZ;  // Gt->Yt

    const short* pa = Ta + (size_t)(ti * 16 + l15) * BSZ + w * 1024 + q * 8;
    const short* pb = Tb + (size_t)(tj * 16 + l15) * BSZ + w * 1024 + q * 8;

    float4v acc[4];
    #pragma unroll
    for (int a = 0; a < 4; ++a) acc[a] = (float4v){0.f, 0.f, 0.f, 0.f};

    #pragma unroll
    for (int kk = 0; kk < 32; kk += 4) {
        #pragma unroll
        for (int a = 0; a < 4; ++a) {
            short8 fa = *(const short8*)&pa[(kk + a) * 32];
            short8 fb = *(const short8*)&pb[(kk + a) * 32];
            acc[a] = __builtin_amdgcn_mfma_f32_16x16x32_bf16(fa, fb, acc[a], 0, 0, 0);
        }
    }

    // D: row(d1 within tile) = q*4+r, col(d2) = l15.
    #pragma unroll
    for (int r = 0; r < 4; ++r)
        red[w][(q * 4 + r) * 16 + l15] = acc[0][r] + acc[1][r] + acc[2][r] + acc[3][r];
    __syncthreads();

    if (tid < 256) {
        const int d1i = tid & 15, d2i = tid >> 4;
        float s = 0.f;
        #pragma unroll
        for (int ww = 0; ww < 8; ++ww) s += red[ww][d1i * 16 + d2i];
        Gb[((size_t)gram << 14) + ((tj * 16 + d2i) << 7) + ti * 16 + d1i]
            = __float2bfloat16(s);
    }
}

// ---------------------------------------------------------------- stage 2
// Per row i: Q = x^T G via MFMA, fold Q.x -> A,B,C; rho; atomicAdd loss.
// Raw fp32 X (normalization folds out of rho). 256 blocks x 4 waves.
// Block owns 32 rows: wave = (rowgrp g = wave&1 -> 16 rows, nt-half
// h = wave>>1 -> 4 of 8 d2-strips). Per-row A/B/C combined across the two
// h-waves in LDS, then wave 0 computes rho and block-reduces.
__global__ __launch_bounds__(256) void quad_k(
    const float* __restrict__ Xt, const float* __restrict__ Xs,
    const __hip_bfloat16* __restrict__ Gb, float* __restrict__ out)
{
    const int tid  = threadIdx.x;
    const int lane = tid & 63;
    const int wave = tid >> 6;
    const int q    = lane >> 4;
    const int l15  = lane & 15;
    const int g    = wave & 1;      // row group within block
    const int h    = wave >> 1;     // nt half
    const int rbase = blockIdx.x * 32 + g * 16;

    // A-frags: lane holds X[rbase+l15][kk*32+q*8 ..+8) as bf16
    short8 At[4], As[4];
    #pragma unroll
    for (int kk = 0; kk < 4; ++kk) {
        const float* pt = Xt + (size_t)(rbase + l15) * DIM + kk * 32 + q * 8;
        const float* ps = Xs + (size_t)(rbase + l15) * DIM + kk * 32 + q * 8;
        float4 t0 = *(const float4*)pt, t1 = *(const float4*)(pt + 4);
        float4 s0 = *(const float4*)ps, s1 = *(const float4*)(ps + 4);
        short8 a, b;
        a[0]=f2bf(t0.x); a[1]=f2bf(t0.y); a[2]=f2bf(t0.z); a[3]=f2bf(t0.w);
        a[4]=f2bf(t1.x); a[5]=f2bf(t1.y); a[6]=f2bf(t1.z); a[7]=f2bf(t1.w);
        b[0]=f2bf(s0.x); b[1]=f2bf(s0.y); b[2]=f2bf(s0.z); b[3]=f2bf(s0.w);
        b[4]=f2bf(s1.x); b[5]=f2bf(s1.y); b[6]=f2bf(s1.z); b[7]=f2bf(s1.w);
        At[kk] = a; As[kk] = b;
    }

    float fA[4] = {0,0,0,0}, fB[4] = {0,0,0,0}, fC[4] = {0,0,0,0};
    const short* G = (const short*)Gb;

    #pragma unroll
    for (int nti = 0; nti < 4; ++nti) {
        int d2 = (h * 4 + nti) * 16 + l15;
        float4v qt = {0.f,0.f,0.f,0.f}, qs = qt, qc = qt;
        #pragma unroll
        for (int kk = 0; kk < 4; ++kk) {
            int off = (d2 << 7) + kk * 32 + q * 8;
            short8 Bt = *(const short8*)&G[off];
            short8 Bs = *(const short8*)&G[16384 + off];
            short8 Bm = *(const short8*)&G[32768 + off];
            qt = __builtin_amdgcn_mfma_f32_16x16x32_bf16(At[kk], Bt, qt, 0, 0, 0);
            qs = __builtin_amdgcn_mfma_f32_16x16x32_bf16(As[kk], Bs, qs, 0, 0, 0);
            qc = __builtin_amdgcn_mfma_f32_16x16x32_bf16(At[kk], Bm, qc, 0, 0, 0);
        }
        // fold: D row = q*4+r, col = l15 -> Q[row][d2]; A += Q*x, etc.
        #pragma unroll
        for (int r = 0; r < 4; ++r) {
            int row = rbase + q * 4 + r;
            float xtv = Xt[(size_t)row * DIM + d2];
            float xsv = Xs[(size_t)row * DIM + d2];
            fA[r] += qt[r] * xtv;
            fB[r] += qs[r] * xsv;
            fC[r] += qc[r] * xsv;
        }
    }

    // 16-lane reduce per r -> per-row partials at l15==0; combine h-halves
    // via LDS. cmb[g][row][h*4 + {A,B,C}] (stride 8 floats, conflict-free).
    __shared__ float cmb[2][16][8];
    #pragma unroll
    for (int r = 0; r < 4; ++r) {
        float A = fA[r], B = fB[r], C = fC[r];
        #pragma unroll
        for (int off = 1; off < 16; off <<= 1) {
            A += __shfl_xor(A, off);
            B += __shfl_xor(B, off);
            C += __shfl_xor(C, off);
        }
        if (l15 == 0) {
            cmb[g][q * 4 + r][h * 4 + 0] = A;
            cmb[g][q * 4 + r][h * 4 + 1] = B;
            cmb[g][q * 4 + r][h * 4 + 2] = C;
        }
    }
    __syncthreads();

    if (wave == 0) {
        float wl = 0.f;
        if (tid < 32) {
            int gg = tid >> 4, row = tid & 15;
            float A = cmb[gg][row][0] + cmb[gg][row][4];
            float B = cmb[gg][row][1] + cmb[gg][row][5];
            float C = cmb[gg][row][2] + cmb[gg][row][6];
            wl = 2.f - 2.f * C * rsqrtf(A * B);
        }
        #pragma unroll
        for (int off = 1; off < 64; off <<= 1) wl += __shfl_xor(wl, off);
        if (tid == 0) atomicAdd(out, wl * INV_B2);
    }
}

// ---------------------------------------------------------------- launch
extern "C" void kernel_launch(void* const* d_in, const int* in_sizes, int n_in,
                              void* d_out, int out_size, void* d_ws, size_t ws_size,
                              hipStream_t stream) {
    const float* zxs = (const float*)d_in[0];
    const float* zys = (const float*)d_in[1];
    const float* zxt = (const float*)d_in[2];
    const float* zyt = (const float*)d_in[3];
    // d_in[4] = temperature: folds out of rho, unused.
    float* out = (float*)d_out;

    char* ws = (char*)d_ws;
    short* YT = (short*)ws;                                    // 2 x 128 x 8192 bf16 = 4 MB
    __hip_bfloat16* Gb = (__hip_bfloat16*)(ws + (size_t)4 * 1024 * 1024);  // 3*16384 bf16

    prep       <<<dim3(256, 2), 256, 0, stream>>>(zyt, zys, YT, out);
    gram_direct<<<192,          512, 0, stream>>>(YT, Gb);
    quad_k     <<<256,          256, 0, stream>>>(zxt, zxs, Gb, out);
}